// Round 1
// baseline (1160.071 us; speedup 1.0000x reference)
//
#include <hip/hip_runtime.h>
#include <math.h>

// ---------------------------------------------------------------------------
// EquivariantNet forward — fused HIP implementation.
// Shapes: N=8192, E=131072, C=16, Fe=16, mid=16, KV=16, ckv=8, Co=8, HEADS=4, L=2
// ---------------------------------------------------------------------------

// ---------------- CSR build over edge_dst ----------------
__global__ void k_zero(int* p, int n) {
    int i = blockIdx.x * 256 + threadIdx.x;
    if (i < n) p[i] = 0;
}

__global__ void k_hist(const int* __restrict__ dst, int* __restrict__ counts, int E) {
    int e = blockIdx.x * 256 + threadIdx.x;
    if (e < E) atomicAdd(&counts[dst[e]], 1);
}

__global__ __launch_bounds__(1024) void k_scan(const int* __restrict__ counts,
                                               int* __restrict__ rowptr,
                                               int* __restrict__ cursor,
                                               int N, int CH) {
    __shared__ int part[1024];
    int t = threadIdx.x;
    int s = 0;
    for (int i = 0; i < CH; ++i) {
        int idx = t * CH + i;
        if (idx < N) s += counts[idx];
    }
    part[t] = s;
    __syncthreads();
    for (int off = 1; off < 1024; off <<= 1) {
        int v = (t >= off) ? part[t - off] : 0;
        __syncthreads();
        part[t] += v;
        __syncthreads();
    }
    int run = (t == 0) ? 0 : part[t - 1];
    for (int i = 0; i < CH; ++i) {
        int idx = t * CH + i;
        if (idx < N) {
            rowptr[idx] = run;
            cursor[idx] = run;
            run += counts[idx];
        }
    }
    if (t == 0) rowptr[N] = part[1023];
}

__global__ void k_scatter(const int* __restrict__ dst, int* __restrict__ cursor,
                          int* __restrict__ eids, int E) {
    int e = blockIdx.x * 256 + threadIdx.x;
    if (e < E) {
        int pos = atomicAdd(&cursor[dst[e]], 1);
        eids[pos] = e;
    }
}

// ---------------- init x working copies ----------------
__global__ void k_initx(const float* __restrict__ x0, const float* __restrict__ x1,
                        float* __restrict__ xs0, float* __restrict__ xs1, int n0, int n1) {
    int i = blockIdx.x * 256 + threadIdx.x;
    if (i < n0) xs0[i] = x0[i];
    else if (i < n0 + n1) xs1[i - n0] = x1[i - n0];
}

// ---------------- conv: nf1 pairs (0->0, 1->0, 0->1) ----------------
// thread = (edge, oo). Weights in LDS, o-major padded for b128-friendly reads.
template <int KVO>
__global__ __launch_bounds__(256) void k_convA(
    int E, int nGroups,
    const float* __restrict__ ef, const float* __restrict__ b00,
    const float* __restrict__ b01, const float* __restrict__ b10,
    const int* __restrict__ src,
    const float* __restrict__ xs0, const float* __restrict__ xs1,
    const float* __restrict__ w1,     // rows 0..2 of (4,16,16): [pp][f][h]
    const float* __restrict__ w2nf1,  // (3,16,KVO,16): [pp][h][oo][i]
    float* __restrict__ out0,         // (E,KVO)
    float* __restrict__ out1)         // (E,KVO,3) — written (=)
{
    constexpr int EPB = 256 / KVO;
    constexpr int WST = 260;  // 16*16 + 4 pad
    __shared__ float w2L[3 * KVO * WST];
    __shared__ float w1L[768];
    __shared__ float efL[EPB][16];
    __shared__ float x0L[EPB][16];
    __shared__ float x1L[EPB][48];
    __shared__ float bL[EPB][7];  // b00, b01[3], b10[3]
    __shared__ float HL[EPB][3][16];

    int tid = threadIdx.x;
    for (int idx = tid; idx < 3 * 16 * KVO * 16; idx += 256) {
        int i = idx & 15;
        int r = idx >> 4;
        int oo = r % KVO; r /= KVO;
        int h = r & 15;
        int pp = r >> 4;
        w2L[(pp * KVO + oo) * WST + h * 16 + i] = w2nf1[idx];
    }
    for (int idx = tid; idx < 768; idx += 256) w1L[idx] = w1[idx];

    int ee = tid / KVO, oo = tid % KVO;
    for (int g = blockIdx.x; g < nGroups; g += gridDim.x) {
        int e0 = g * EPB;
        __syncthreads();  // protect staging vs previous iteration's readers
        for (int idx = tid; idx < EPB * 16; idx += 256) {
            int a = idx >> 4, c = idx & 15;
            int e = e0 + a;
            int s = src[e];
            efL[a][c] = ef[e * 16 + c];
            x0L[a][c] = xs0[s * 16 + c];
        }
        for (int idx = tid; idx < EPB * 48; idx += 256) {
            int a = idx / 48, k = idx % 48;
            x1L[a][k] = xs1[src[e0 + a] * 48 + k];
        }
        for (int idx = tid; idx < EPB * 7; idx += 256) {
            int a = idx / 7, k = idx % 7;
            int e = e0 + a;
            float v;
            if (k == 0) v = b00[e];
            else if (k < 4) v = b01[e * 3 + (k - 1)];
            else v = b10[e * 3 + (k - 4)];
            bL[a][k] = v;
        }
        __syncthreads();
        // H[p][e][h] = relu(sum_f ef[e,f] * w1[p,f,h])
        for (int idx = tid; idx < EPB * 48; idx += 256) {
            int a = idx / 48, k = idx % 48, pp = k >> 4, h = k & 15;
            float s = 0.f;
#pragma unroll
            for (int f = 0; f < 16; ++f) s += efL[a][f] * w1L[(pp * 16 + f) * 16 + h];
            HL[a][pp][h] = fmaxf(s, 0.f);
        }
        __syncthreads();

        float x0r[16], t10[16];
#pragma unroll
        for (int i = 0; i < 16; ++i) x0r[i] = x0L[ee][i];
        float bq0 = bL[ee][4], bq1 = bL[ee][5], bq2 = bL[ee][6];
#pragma unroll
        for (int i = 0; i < 16; ++i)
            t10[i] = bq0 * x1L[ee][i * 3 + 0] + bq1 * x1L[ee][i * 3 + 1] + bq2 * x1L[ee][i * 3 + 2];

        float g00 = 0.f, g01 = 0.f, g10 = 0.f;
        const float* wp0 = &w2L[(0 * KVO + oo) * WST];
        const float* wp1 = &w2L[(1 * KVO + oo) * WST];
        const float* wp2 = &w2L[(2 * KVO + oo) * WST];
#pragma unroll
        for (int h = 0; h < 16; ++h) {
            float h0 = HL[ee][0][h], h1 = HL[ee][1][h], h2 = HL[ee][2][h];
            float d0 = 0.f, d1 = 0.f, d2 = 0.f;
#pragma unroll
            for (int i = 0; i < 16; ++i) {
                float a0 = wp0[h * 16 + i], a1 = wp1[h * 16 + i], a2 = wp2[h * 16 + i];
                d0 += a0 * x0r[i];
                d1 += a1 * x0r[i];
                d2 += a2 * t10[i];
            }
            g00 += h0 * d0;
            g01 += h1 * d1;
            g10 += h2 * d2;
        }
        int e = e0 + ee;
        out0[e * KVO + oo] = g00 * bL[ee][0] + g10;
        out1[(e * KVO + oo) * 3 + 0] = g01 * bL[ee][1];
        out1[(e * KVO + oo) * 3 + 1] = g01 * bL[ee][2];
        out1[(e * KVO + oo) * 3 + 2] = g01 * bL[ee][3];
    }
}

// ---------------- conv: pair (1->1) with b11 (E,3,3,3) ----------------
template <int KVO>
__global__ __launch_bounds__(256) void k_convB(
    int E, int nGroups,
    const float* __restrict__ ef, const float* __restrict__ b11,
    const int* __restrict__ src, const float* __restrict__ xs1,
    const float* __restrict__ w1p3,  // (16,16) row 3: [f][h]
    const float* __restrict__ w211,  // (16,KVO,16,3): [h][oo][i][f]
    float* __restrict__ out1)        // (E,KVO,3) — accumulated (+=)
{
    constexpr int EPB = 256 / KVO;
    constexpr int WST = 772;  // 3*16*16 + 4 pad
    __shared__ float w2L[KVO * WST];
    __shared__ float w1L[256];
    __shared__ float efL[EPB][16];
    __shared__ float x1L[EPB][48];
    __shared__ float b11L[EPB][27];
    __shared__ float HL[EPB][16];

    int tid = threadIdx.x;
    for (int idx = tid; idx < 16 * KVO * 16 * 3; idx += 256) {
        int f = idx % 3;
        int r = idx / 3;
        int i = r & 15; r >>= 4;
        int oo = r % KVO;
        int h = r / KVO;
        w2L[oo * WST + (f * 16 + h) * 16 + i] = w211[idx];
    }
    for (int idx = tid; idx < 256; idx += 256) w1L[idx] = w1p3[idx];

    int ee = tid / KVO, oo = tid % KVO;
    for (int g = blockIdx.x; g < nGroups; g += gridDim.x) {
        int e0 = g * EPB;
        __syncthreads();
        for (int idx = tid; idx < EPB * 16; idx += 256) {
            int a = idx >> 4, c = idx & 15;
            efL[a][c] = ef[(e0 + a) * 16 + c];
        }
        for (int idx = tid; idx < EPB * 48; idx += 256) {
            int a = idx / 48, k = idx % 48;
            x1L[a][k] = xs1[src[e0 + a] * 48 + k];
        }
        for (int idx = tid; idx < EPB * 27; idx += 256) {
            int a = idx / 27, k = idx % 27;
            b11L[a][k] = b11[(e0 + a) * 27 + k];
        }
        __syncthreads();
        for (int idx = tid; idx < EPB * 16; idx += 256) {
            int a = idx >> 4, h = idx & 15;
            float s = 0.f;
#pragma unroll
            for (int f = 0; f < 16; ++f) s += efL[a][f] * w1L[f * 16 + h];
            HL[a][h] = fmaxf(s, 0.f);
        }
        __syncthreads();

        float x1r[48];
#pragma unroll
        for (int i = 0; i < 48; ++i) x1r[i] = x1L[ee][i];
        float G[3][3];  // [q][f]
        const float* wp = &w2L[oo * WST];
#pragma unroll
        for (int f = 0; f < 3; ++f) {
            float R[16];
#pragma unroll
            for (int i = 0; i < 16; ++i) R[i] = 0.f;
#pragma unroll
            for (int h = 0; h < 16; ++h) {
                float hv = HL[ee][h];
#pragma unroll
                for (int i = 0; i < 16; ++i) R[i] += hv * wp[(f * 16 + h) * 16 + i];
            }
#pragma unroll
            for (int q = 0; q < 3; ++q) {
                float d = 0.f;
#pragma unroll
                for (int i = 0; i < 16; ++i) d += R[i] * x1r[i * 3 + q];
                G[q][f] = d;
            }
        }
        int e = e0 + ee;
#pragma unroll
        for (int p = 0; p < 3; ++p) {
            float s = 0.f;
#pragma unroll
            for (int q = 0; q < 3; ++q)
#pragma unroll
                for (int f = 0; f < 3; ++f) s += G[q][f] * b11L[ee][p * 9 + q * 3 + f];
            out1[(e * KVO + oo) * 3 + p] += s;
        }
    }
}

// ---------------- q projection ----------------
__global__ void k_q(int N, const float* __restrict__ xs0, const float* __restrict__ xs1,
                    const float* __restrict__ wq,  // (2,16,8) for this layer
                    float* __restrict__ q0, float* __restrict__ q1) {
    int t = blockIdx.x * 256 + threadIdx.x;
    if (t >= N * 32) return;
    int n = t >> 5, comp = t & 31;
    if (comp < 8) {
        float a = 0.f;
#pragma unroll
        for (int c = 0; c < 16; ++c) a += xs0[n * 16 + c] * wq[c * 8 + comp];
        q0[n * 8 + comp] = a;
    } else {
        int idx = comp - 8, dd = idx / 3, mm = idx % 3;
        float a = 0.f;
#pragma unroll
        for (int c = 0; c < 16; ++c) a += xs1[n * 48 + c * 3 + mm] * wq[128 + c * 8 + dd];
        q1[n * 24 + dd * 3 + mm] = a;
    }
}

// ---------------- attention logits z ----------------
__global__ void k_z(int E, const int* __restrict__ dst,
                    const float* __restrict__ kv0, const float* __restrict__ kv1,
                    const float* __restrict__ q0, const float* __restrict__ q1,
                    float* __restrict__ z) {
    int e = blockIdx.x * 256 + threadIdx.x;
    if (e >= E) return;
    int n = dst[e];
    float z0 = 0.f, z1 = 0.f, z2 = 0.f, z3 = 0.f;
#pragma unroll
    for (int d = 0; d < 8; ++d) {
        float t = q0[n * 8 + d] * kv0[e * 16 + d];
#pragma unroll
        for (int m = 0; m < 3; ++m) t += q1[(n * 8 + d) * 3 + m] * kv1[(e * 16 + d) * 3 + m];
        if (d < 2) z0 += t;
        else if (d < 4) z1 += t;
        else if (d < 6) z2 += t;
        else z3 += t;
    }
    const float scale = 0.35355339059327373f;  // 1/sqrt(8)
    z[e * 4 + 0] = z0 * scale;
    z[e * 4 + 1] = z1 * scale;
    z[e * 4 + 2] = z2 * scale;
    z[e * 4 + 3] = z3 * scale;
}

// ---------------- per-node: softmax + aggregate + proj + SE3-norm ----------------
__global__ __launch_bounds__(256) void k_attn(
    int N,
    const int* __restrict__ rowptr, const int* __restrict__ eids,
    const float* __restrict__ z, const float* __restrict__ kv0, const float* __restrict__ kv1,
    const float* __restrict__ wproj,  // (2,24,16)
    const float* __restrict__ gamma, const float* __restrict__ beta,  // (2,16)
    float* __restrict__ xs0, float* __restrict__ xs1) {
    __shared__ float wpL[768];
    __shared__ float gL[32], btL[32];
    __shared__ float inb[4][100];  // per-wave: in0[24] + in1[24*3]
    int tid = threadIdx.x;
    for (int i = tid; i < 768; i += 256) wpL[i] = wproj[i];
    if (tid < 32) { gL[tid] = gamma[tid]; btL[tid] = beta[tid]; }
    int wave = tid >> 6, lane = tid & 63;
    int n = blockIdx.x * 4 + wave;
    int base = rowptr[n], deg = rowptr[n + 1] - base;

    // segment softmax stats (per head)
    float mx0 = -INFINITY, mx1 = -INFINITY, mx2 = -INFINITY, mx3 = -INFINITY;
    for (int j = lane; j < deg; j += 64) {
        int e = eids[base + j];
        float4 zv = *(const float4*)&z[e * 4];
        mx0 = fmaxf(mx0, zv.x); mx1 = fmaxf(mx1, zv.y);
        mx2 = fmaxf(mx2, zv.z); mx3 = fmaxf(mx3, zv.w);
    }
    for (int off = 1; off < 64; off <<= 1) {
        mx0 = fmaxf(mx0, __shfl_xor(mx0, off));
        mx1 = fmaxf(mx1, __shfl_xor(mx1, off));
        mx2 = fmaxf(mx2, __shfl_xor(mx2, off));
        mx3 = fmaxf(mx3, __shfl_xor(mx3, off));
    }
    if (!isfinite(mx0)) mx0 = 0.f;
    if (!isfinite(mx1)) mx1 = 0.f;
    if (!isfinite(mx2)) mx2 = 0.f;
    if (!isfinite(mx3)) mx3 = 0.f;
    float s0 = 0.f, s1 = 0.f, s2 = 0.f, s3 = 0.f;
    for (int j = lane; j < deg; j += 64) {
        int e = eids[base + j];
        float4 zv = *(const float4*)&z[e * 4];
        s0 += __expf(zv.x - mx0); s1 += __expf(zv.y - mx1);
        s2 += __expf(zv.z - mx2); s3 += __expf(zv.w - mx3);
    }
    for (int off = 1; off < 64; off <<= 1) {
        s0 += __shfl_xor(s0, off); s1 += __shfl_xor(s1, off);
        s2 += __shfl_xor(s2, off); s3 += __shfl_xor(s3, off);
    }
    float mxa[4] = {mx0, mx1, mx2, mx3};
    float inva[4] = {1.f / (s0 + 1e-9f), 1.f / (s1 + 1e-9f),
                     1.f / (s2 + 1e-9f), 1.f / (s3 + 1e-9f)};

    // o accumulation: lanes 0..31 own the 32 attention-output components
    int kk = lane >> 3, d = lane & 7, h = d >> 1;
    float acc = 0.f;
    if (lane < 32) {
        float mh = mxa[h], ih = inva[h];
        for (int j = 0; j < deg; ++j) {
            int e = eids[base + j];
            float w = __expf(z[e * 4 + h] - mh) * ih;
            float v = (kk == 0) ? kv0[e * 16 + 8 + d] : kv1[(e * 16 + 8 + d) * 3 + (kk - 1)];
            acc += w * v;
        }
    }
    // stage concat([o, x]) into LDS
    float* in0 = &inb[wave][0];   // [24]
    float* in1 = &inb[wave][24];  // [24][3]
    if (lane < 8) in0[lane] = acc;
    else if (lane < 32) in1[d * 3 + (kk - 1)] = acc;
    if (lane < 16) in0[8 + lane] = xs0[n * 16 + lane];
    if (lane < 48) in1[24 + lane] = xs1[n * 48 + lane];
    __syncthreads();

    // projection: 64 lanes -> 64 outputs (16 for x0, 48 for x1)
    int kind = (lane < 16) ? 0 : 1;
    int c = lane & 15, mm = (lane >> 4) - 1;
    float y = 0.f;
    if (kind == 0) {
#pragma unroll
        for (int j = 0; j < 24; ++j) y += in0[j] * wpL[j * 16 + c];
    } else {
#pragma unroll
        for (int j = 0; j < 24; ++j) y += in1[j * 3 + mm] * wpL[384 + j * 16 + c];
    }
    // SE(3) norm
    float sq = (kind == 0) ? 0.f : y * y;
    sq += __shfl_xor(sq, 16);
    sq += __shfl_xor(sq, 32);
    float nrm = (kind == 0) ? sqrtf(y * y + 1e-12f) : sqrtf(sq + 1e-12f);
    float mu = nrm;
    mu += __shfl_xor(mu, 1); mu += __shfl_xor(mu, 2);
    mu += __shfl_xor(mu, 4); mu += __shfl_xor(mu, 8);
    mu *= 0.0625f;
    float dv = nrm - mu;
    float var = dv * dv;
    var += __shfl_xor(var, 1); var += __shfl_xor(var, 2);
    var += __shfl_xor(var, 4); var += __shfl_xor(var, 8);
    var *= 0.0625f;
    float ln = dv * rsqrtf(var + 1e-5f) * gL[kind * 16 + c] + btL[kind * 16 + c];
    float fac = fmaxf(ln, 0.f) / (nrm + 1e-3f);
    y *= fac;
    if (kind == 0) xs0[n * 16 + c] = y;
    else xs1[n * 48 + c * 3 + mm] = y;
}

// ---------------- final output: segment-sum(m) + x @ wself ----------------
__global__ __launch_bounds__(256) void k_out(
    int N,
    const int* __restrict__ rowptr, const int* __restrict__ eids,
    const float* __restrict__ m0f, const float* __restrict__ m1f,
    const float* __restrict__ xs0, const float* __restrict__ xs1,
    const float* __restrict__ wself,  // (2,16,8)
    float* __restrict__ out) {
    int tid = threadIdx.x;
    int wave = tid >> 6, lane = tid & 63;
    int n = blockIdx.x * 4 + wave;
    if (lane >= 32) return;
    int kk = lane >> 3, d = lane & 7;
    int base = rowptr[n], deg = rowptr[n + 1] - base;
    float acc = 0.f;
    for (int j = 0; j < deg; ++j) {
        int e = eids[base + j];
        acc += (kk == 0) ? m0f[e * 8 + d] : m1f[(e * 8 + d) * 3 + (kk - 1)];
    }
    if (kk == 0) {
#pragma unroll
        for (int c = 0; c < 16; ++c) acc += xs0[n * 16 + c] * wself[c * 8 + d];
    } else {
        int mm = kk - 1;
#pragma unroll
        for (int c = 0; c < 16; ++c) acc += xs1[n * 48 + c * 3 + mm] * wself[128 + c * 8 + d];
    }
    out[n * 32 + ((kk == 0) ? d : (8 + d * 3 + (kk - 1)))] = acc;
}

// ---------------------------------------------------------------------------
extern "C" void kernel_launch(void* const* d_in, const int* in_sizes, int n_in,
                              void* d_out, int out_size, void* d_ws, size_t ws_size,
                              hipStream_t stream) {
    const float* x0 = (const float*)d_in[0];
    const float* x1 = (const float*)d_in[1];
    const float* ef = (const float*)d_in[2];
    const float* b00 = (const float*)d_in[3];
    const float* b01 = (const float*)d_in[4];
    const float* b10 = (const float*)d_in[5];
    const float* b11 = (const float*)d_in[6];
    const float* kvw1 = (const float*)d_in[7];    // (2,4,16,16)
    const float* kvw2n = (const float*)d_in[8];   // (2,3,16,16,16)
    const float* kvw211 = (const float*)d_in[9];  // (2,16,16,16,3)
    const float* wq = (const float*)d_in[10];     // (2,2,16,8)
    const float* wproj = (const float*)d_in[11];  // (2,2,24,16)
    const float* gam = (const float*)d_in[12];    // (2,2,16)
    const float* bet = (const float*)d_in[13];
    const float* fcw1 = (const float*)d_in[14];    // (4,16,16)
    const float* fcw2n = (const float*)d_in[15];   // (3,16,8,16)
    const float* fcw211 = (const float*)d_in[16];  // (16,8,16,3)
    const float* fcself = (const float*)d_in[17];  // (2,16,8)
    const int* esrc = (const int*)d_in[18];
    const int* edst = (const int*)d_in[19];
    int N = in_sizes[0] / 16;
    int E = in_sizes[18];
    float* out = (float*)d_out;

    float* ws = (float*)d_ws;
    size_t off = 0;
    float* xs0 = ws + off; off += (size_t)N * 16;
    float* xs1 = ws + off; off += (size_t)N * 48;
    float* q0b = ws + off; off += (size_t)N * 8;
    float* q1b = ws + off; off += (size_t)N * 24;
    float* kv0 = ws + off; off += (size_t)E * 16;
    float* kv1 = ws + off; off += (size_t)E * 48;
    float* zb = ws + off; off += (size_t)E * 4;
    float* m0f = ws + off; off += (size_t)E * 8;
    float* m1f = ws + off; off += (size_t)E * 24;
    int* counts = (int*)(ws + off); off += N;
    int* rowptr = (int*)(ws + off); off += N + 1;
    int* cursor = (int*)(ws + off); off += N;
    int* eids = (int*)(ws + off); off += E;

    const int tpb = 256;
    // CSR over edge_dst
    k_zero<<<(N + 255) / 256, tpb, 0, stream>>>(counts, N);
    k_hist<<<(E + 255) / 256, tpb, 0, stream>>>(edst, counts, E);
    int CH = (N + 1023) / 1024;
    k_scan<<<1, 1024, 0, stream>>>(counts, rowptr, cursor, N, CH);
    k_scatter<<<(E + 255) / 256, tpb, 0, stream>>>(edst, cursor, eids, E);
    k_initx<<<(N * 64 + 255) / 256, tpb, 0, stream>>>(x0, x1, xs0, xs1, N * 16, N * 48);

    for (int l = 0; l < 2; ++l) {
        k_q<<<(N * 32 + 255) / 256, tpb, 0, stream>>>(N, xs0, xs1, wq + l * 256, q0b, q1b);
        int ng16 = E / 16;
        k_convA<16><<<512, tpb, 0, stream>>>(E, ng16, ef, b00, b01, b10, esrc, xs0, xs1,
                                             kvw1 + l * 1024, kvw2n + l * 12288, kv0, kv1);
        k_convB<16><<<512, tpb, 0, stream>>>(E, ng16, ef, b11, esrc, xs1,
                                             kvw1 + l * 1024 + 768, kvw211 + l * 12288, kv1);
        k_z<<<(E + 255) / 256, tpb, 0, stream>>>(E, edst, kv0, kv1, q0b, q1b, zb);
        k_attn<<<N / 4, tpb, 0, stream>>>(N, rowptr, eids, zb, kv0, kv1,
                                          wproj + l * 768, gam + l * 32, bet + l * 32, xs0, xs1);
    }
    int ng32 = E / 32;
    k_convA<8><<<512, tpb, 0, stream>>>(E, ng32, ef, b00, b01, b10, esrc, xs0, xs1,
                                        fcw1, fcw2n, m0f, m1f);
    k_convB<8><<<512, tpb, 0, stream>>>(E, ng32, ef, b11, esrc, xs1,
                                        fcw1 + 768, fcw211, m1f);
    k_out<<<N / 4, tpb, 0, stream>>>(N, rowptr, eids, m0f, m1f, xs0, xs1, fcself, out);
}